// Round 6
// baseline (171.744 us; speedup 1.0000x reference)
//
#include <hip/hip_runtime.h>

// Problem constants (fixed by reference setup_inputs)
#define NB 4
#define NC 64
#define NH 256
#define NW 256
#define HW (NH * NW)            // 65536 floats per (b,c) plane
#define CPW 16                  // channels per wave (NC / 4 waves)

__device__ __forceinline__ float4 f4zero() { return make_float4(0.f, 0.f, 0.f, 0.f); }

// Fused kernel: one block = one image row (b,h). 4 waves; wave wv handles
// channels [wv*16, wv*16+16). Lane owns 4 consecutive w (float4); horizontal
// neighbors via shuffles. Channel loop is software-pipelined with explicit
// A/B register double-buffering so ~8 global loads stay in flight per wave
// (the round-4 profile showed ~1 cache-latency per iteration, serialized:
// VALUBusy 17%, hbm 19%, all pipes idle -> latency-bound).
__global__ __launch_bounds__(256, 4) void k_fused(
    const float* __restrict__ img, const float* __restrict__ ev,
    float* __restrict__ out)
{
    __shared__ float red[2][48][64];   // two reduction slots, [value][lane]

    const int lane = threadIdx.x & 63;
    const int wv   = threadIdx.x >> 6;           // 0..3 = channel chunk

    // XCD-aware swizzle: 1024 blocks, 8 XCDs -> contiguous 128-row chunks per
    // XCD so h-adjacent rows (which share img rows) live on the same L2.
    const int bid = blockIdx.x;
    const int swz = (bid & 7) * 128 + (bid >> 3);   // bijective, 1024 % 8 == 0
    const int b = swz >> 8;
    const int h = swz & 255;
    const int w = lane << 2;

    const bool hm = (h > 0);
    const bool hp = (h < NH - 1);

    const size_t base = (size_t)b * NC * HW + (size_t)(wv * CPW) * HW
                      + (size_t)h * NW + w;
    const float* ibase = img + base;
    const float* ebase = ev + base;

    float acc[8][4];
    float si[3][4];
    float se[4];
#pragma unroll
    for (int k = 0; k < 8; ++k)
#pragma unroll
        for (int x = 0; x < 4; ++x) acc[k][x] = 0.f;
#pragma unroll
    for (int r = 0; r < 3; ++r)
#pragma unroll
        for (int x = 0; x < 4; ++x) si[r][x] = 0.f;
#pragma unroll
    for (int x = 0; x < 4; ++x) se[x] = 0.f;

    // ---- software-pipelined channel loop (ping-pong A/B staging) ----
    float4 Am, Az, Ap, Ae, Bm, Bz, Bp, Be;

#define LOADSET(M, Z, P, E, c)                                              \
    {                                                                       \
        const float* p_ = ibase + (size_t)(c) * HW;                         \
        M = hm ? *(const float4*)(p_ - NW) : f4zero();                      \
        Z = *(const float4*)(p_);                                           \
        P = hp ? *(const float4*)(p_ + NW) : f4zero();                      \
        E = *(const float4*)(ebase + (size_t)(c) * HW);                     \
    }

#define COMPUTESET(M, Z, P, E)                                              \
    {                                                                       \
        float lm = __shfl_up(M.w, 1);                                       \
        float lz = __shfl_up(Z.w, 1);                                       \
        float lp = __shfl_up(P.w, 1);                                       \
        float rm = __shfl_down(M.x, 1);                                     \
        float rz = __shfl_down(Z.x, 1);                                     \
        float rp = __shfl_down(P.x, 1);                                     \
        if (lane == 0)  { lm = 0.f; lz = 0.f; lp = 0.f; }                   \
        if (lane == 63) { rm = 0.f; rz = 0.f; rp = 0.f; }                   \
        float m6[6] = { lm, M.x, M.y, M.z, M.w, rm };                       \
        float z6[6] = { lz, Z.x, Z.y, Z.z, Z.w, rz };                       \
        float p6[6] = { lp, P.x, P.y, P.z, P.w, rp };                       \
        float sqm[6], sqz[6], sqp[6];                                       \
        for (int i = 0; i < 6; ++i) {                                       \
            sqm[i] = m6[i] * m6[i];                                         \
            sqz[i] = z6[i] * z6[i];                                         \
            sqp[i] = p6[i] * p6[i];                                         \
        }                                                                   \
        for (int x = 0; x < 4; ++x) {                                       \
            si[0][x] += sqm[x + 1];                                         \
            si[1][x] += sqz[x + 1];                                         \
            si[2][x] += sqp[x + 1];                                         \
        }                                                                   \
        se[0] = fmaf(E.x, E.x, se[0]);                                      \
        se[1] = fmaf(E.y, E.y, se[1]);                                      \
        se[2] = fmaf(E.z, E.z, se[2]);                                      \
        se[3] = fmaf(E.w, E.w, se[3]);                                      \
        float pe[4] = { z6[1] * E.x, z6[2] * E.y, z6[3] * E.z, z6[4] * E.w };\
        for (int x = 0; x < 4; ++x) {                                       \
            acc[0][x] = fmaf(sqm[x],     pe[x], acc[0][x]);                 \
            acc[1][x] = fmaf(sqm[x + 1], pe[x], acc[1][x]);                 \
            acc[2][x] = fmaf(sqm[x + 2], pe[x], acc[2][x]);                 \
            acc[3][x] = fmaf(sqz[x],     pe[x], acc[3][x]);                 \
            acc[4][x] = fmaf(sqz[x + 2], pe[x], acc[4][x]);                 \
            acc[5][x] = fmaf(sqp[x],     pe[x], acc[5][x]);                 \
            acc[6][x] = fmaf(sqp[x + 1], pe[x], acc[6][x]);                 \
            acc[7][x] = fmaf(sqp[x + 2], pe[x], acc[7][x]);                 \
        }                                                                   \
    }

    LOADSET(Am, Az, Ap, Ae, 0);
#pragma unroll
    for (int c = 0; c < CPW; c += 2) {
        LOADSET(Bm, Bz, Bp, Be, c + 1);       // B loads in flight during A compute
        COMPUTESET(Am, Az, Ap, Ae);
        if (c + 2 < CPW) LOADSET(Am, Az, Ap, Ae, c + 2);  // A loads during B compute
        COMPUTESET(Bm, Bz, Bp, Be);
    }
#undef LOADSET
#undef COMPUTESET

    // ---- cross-wave tree reduction through LDS (48 floats per lane) ----
    if (wv >= 2) {
        const int s = wv - 2;
#pragma unroll
        for (int k = 0; k < 8; ++k)
#pragma unroll
            for (int x = 0; x < 4; ++x) red[s][k * 4 + x][lane] = acc[k][x];
#pragma unroll
        for (int r = 0; r < 3; ++r)
#pragma unroll
            for (int x = 0; x < 4; ++x) red[s][32 + r * 4 + x][lane] = si[r][x];
#pragma unroll
        for (int x = 0; x < 4; ++x) red[s][44 + x][lane] = se[x];
    }
    __syncthreads();
    if (wv < 2) {
        const int s = wv;
#pragma unroll
        for (int k = 0; k < 8; ++k)
#pragma unroll
            for (int x = 0; x < 4; ++x) acc[k][x] += red[s][k * 4 + x][lane];
#pragma unroll
        for (int r = 0; r < 3; ++r)
#pragma unroll
            for (int x = 0; x < 4; ++x) si[r][x] += red[s][32 + r * 4 + x][lane];
#pragma unroll
        for (int x = 0; x < 4; ++x) se[x] += red[s][44 + x][lane];
    }
    __syncthreads();
    if (wv == 1) {
#pragma unroll
        for (int k = 0; k < 8; ++k)
#pragma unroll
            for (int x = 0; x < 4; ++x) red[0][k * 4 + x][lane] = acc[k][x];
#pragma unroll
        for (int r = 0; r < 3; ++r)
#pragma unroll
            for (int x = 0; x < 4; ++x) red[0][32 + r * 4 + x][lane] = si[r][x];
#pragma unroll
        for (int x = 0; x < 4; ++x) red[0][44 + x][lane] = se[x];
    }
    __syncthreads();
    if (wv != 0) return;

#pragma unroll
    for (int k = 0; k < 8; ++k)
#pragma unroll
        for (int x = 0; x < 4; ++x) acc[k][x] += red[0][k * 4 + x][lane];
#pragma unroll
    for (int r = 0; r < 3; ++r)
#pragma unroll
        for (int x = 0; x < 4; ++x) si[r][x] += red[0][32 + r * 4 + x][lane];
#pragma unroll
    for (int x = 0; x < 4; ++x) se[x] += red[0][44 + x][lane];

    // ---- epilogue (wave 0 only): reciprocal norms, windows, scale, relu ----
    float rnm[4], rnz[4], rnp[4], rne[4];
#pragma unroll
    for (int x = 0; x < 4; ++x) {
        rnm[x] = 1.f / fmaxf(sqrtf(si[0][x]), 1e-12f);
        rnz[x] = 1.f / fmaxf(sqrtf(si[1][x]), 1e-12f);
        rnp[x] = 1.f / fmaxf(sqrtf(si[2][x]), 1e-12f);
        rne[x] = 1.f / fmaxf(sqrtf(se[x]), 1e-12f);
    }

    float lnm = __shfl_up(rnm[3], 1);
    float lnz = __shfl_up(rnz[3], 1);
    float lnp = __shfl_up(rnp[3], 1);
    float rnm_ = __shfl_down(rnm[0], 1);
    float rnz_ = __shfl_down(rnz[0], 1);
    float rnp_ = __shfl_down(rnp[0], 1);
    if (lane == 0)  { lnm = 0.f; lnz = 0.f; lnp = 0.f; }
    if (lane == 63) { rnm_ = 0.f; rnz_ = 0.f; rnp_ = 0.f; }

    float nm6[6] = { lnm, rnm[0], rnm[1], rnm[2], rnm[3], rnm_ };
    float nz6[6] = { lnz, rnz[0], rnz[1], rnz[2], rnz[3], rnz_ };
    float np6[6] = { lnp, rnp[0], rnp[1], rnp[2], rnp[3], rnp_ };

    float ctr[4];
#pragma unroll
    for (int x = 0; x < 4; ++x) ctr[x] = nz6[x + 1] * rne[x];

    float* outp = out + (((size_t)b * 8) * NH + h) * NW + w;
#pragma unroll
    for (int k = 0; k < 8; ++k) {
        float nbv[4];
#pragma unroll
        for (int x = 0; x < 4; ++x) {
            float v;
            switch (k) {
                case 0: v = nm6[x];     break;
                case 1: v = nm6[x + 1]; break;
                case 2: v = nm6[x + 2]; break;
                case 3: v = nz6[x];     break;
                case 4: v = nz6[x + 2]; break;
                case 5: v = np6[x];     break;
                case 6: v = np6[x + 1]; break;
                default: v = np6[x + 2]; break;
            }
            nbv[x] = v;
        }
        float4 o;
        o.x = fmaxf(acc[k][0] * (nbv[0] * nbv[0]) * ctr[0], 0.f);
        o.y = fmaxf(acc[k][1] * (nbv[1] * nbv[1]) * ctr[1], 0.f);
        o.z = fmaxf(acc[k][2] * (nbv[2] * nbv[2]) * ctr[2], 0.f);
        o.w = fmaxf(acc[k][3] * (nbv[3] * nbv[3]) * ctr[3], 0.f);
        *(float4*)(outp + (size_t)k * NH * NW) = o;
    }
}

extern "C" void kernel_launch(void* const* d_in, const int* in_sizes, int n_in,
                              void* d_out, int out_size, void* d_ws, size_t ws_size,
                              hipStream_t stream) {
    (void)in_sizes; (void)n_in; (void)out_size; (void)d_ws; (void)ws_size;
    const float* img = (const float*)d_in[0];
    const float* ev  = (const float*)d_in[1];
    float* out = (float*)d_out;

    // 1024 blocks (one per row), 256 threads (4 waves x 16 channels)
    k_fused<<<NB * NH, 256, 0, stream>>>(img, ev, out);
}

// Round 7
// 45.397 us; speedup vs baseline: 3.7832x; 3.7832x over previous
//
#include <hip/hip_runtime.h>

// Problem constants (fixed by reference setup_inputs)
#define NB 4
#define NC 64
#define NH 256
#define NW 256
#define HW (NH * NW)            // 65536 floats per (b,c) plane
#define CPW 16                  // channels per wave (NC / 4 waves)
// Row split into 2 tiles of 128 pixels; lane owns 2 consecutive w (float2).
// 2048 blocks x 4 waves = 8 blocks/CU -> 32 waves/CU (R4 was grid-capped at 16).

__device__ __forceinline__ float2 f2zero() { return make_float2(0.f, 0.f); }

// Per-lane reduction payload: 16 acc + 6 si + 2 se + 3 halo-left si + 3 halo-right si = 30
#define NV 30

__global__ __launch_bounds__(256) void k_fused(
    const float* __restrict__ img, const float* __restrict__ ev,
    float* __restrict__ out)
{
    __shared__ float red[2][NV][64];   // two reduction slots, [value][lane] (stride-1: conflict-free)

    const int lane = threadIdx.x & 63;
    const int wv   = threadIdx.x >> 6;            // 0..3 = channel chunk

    // XCD-aware swizzle: 2048 blocks, 8 XCDs; same-XCD blocks get consecutive
    // (tile,h) so h-adjacent rows share L2. Bijective (2048 % 8 == 0).
    const int bid = blockIdx.x;
    const int swz = (bid & 7) * 256 + (bid >> 3);
    const int tile = swz & 1;
    const int h    = (swz >> 1) & 255;
    const int b    = swz >> 9;
    const int w0   = tile * 128 + lane * 2;

    const bool hm = (h > 0);
    const bool hp = (h < NH - 1);

    const size_t base = (size_t)b * NC * HW + (size_t)(wv * CPW) * HW
                      + (size_t)h * NW + w0;
    const float* ibase = img + base;
    const float* ebase = ev + base;

    float acc[8][2];                  // 8 offsets x 2 pixels
    float si[3][2];                   // img^2 sums rows h-1,h,h+1 (own pixels)
    float se[2];                      // ev^2 sums (center)
    float shl[3], shr[3];             // halo img^2 sums (valid on lanes 0 / 63)
#pragma unroll
    for (int k = 0; k < 8; ++k) { acc[k][0] = 0.f; acc[k][1] = 0.f; }
#pragma unroll
    for (int r = 0; r < 3; ++r) { si[r][0] = 0.f; si[r][1] = 0.f; shl[r] = 0.f; shr[r] = 0.f; }
    se[0] = 0.f; se[1] = 0.f;

#pragma unroll 2
    for (int c = 0; c < CPW; ++c) {
        const float* p = ibase + (size_t)c * HW;
        float2 zm = hm ? *(const float2*)(p - NW) : f2zero();
        float2 zz = *(const float2*)(p);
        float2 zp = hp ? *(const float2*)(p + NW) : f2zero();
        float2 ee = *(const float2*)(ebase + (size_t)c * HW);

        // halo loads: lane 0 needs w0-1 (exists iff tile==1), lane 63 needs
        // w0+2 (exists iff tile==0). Uniform-per-block outer condition.
        float hlm = 0.f, hlz = 0.f, hlp = 0.f, hrm = 0.f, hrz = 0.f, hrp = 0.f;
        if (tile == 1 && lane == 0) {
            hlz = p[-1];
            if (hm) hlm = p[-NW - 1];
            if (hp) hlp = p[NW - 1];
        }
        if (tile == 0 && lane == 63) {
            hrz = p[2];
            if (hm) hrm = p[-NW + 2];
            if (hp) hrp = p[NW + 2];
        }

        float lm = __shfl_up(zm.y, 1);
        float lz = __shfl_up(zz.y, 1);
        float lp = __shfl_up(zp.y, 1);
        float rm = __shfl_down(zm.x, 1);
        float rz = __shfl_down(zz.x, 1);
        float rp = __shfl_down(zp.x, 1);
        if (lane == 0)  { lm = hlm; lz = hlz; lp = hlp; }
        if (lane == 63) { rm = hrm; rz = hrz; rp = hrp; }

        // 4-wide windows: idx 0..3 = w0-1, w0, w0+1, w0+2
        float m4[4] = { lm, zm.x, zm.y, rm };
        float z4[4] = { lz, zz.x, zz.y, rz };
        float p4[4] = { lp, zp.x, zp.y, rp };
        float sqm[4], sqz[4], sqp[4];
#pragma unroll
        for (int i = 0; i < 4; ++i) {
            sqm[i] = m4[i] * m4[i];
            sqz[i] = z4[i] * z4[i];
            sqp[i] = p4[i] * p4[i];
        }
        // norm sums: own pixels are window idx 1,2
#pragma unroll
        for (int x = 0; x < 2; ++x) {
            si[0][x] += sqm[x + 1];
            si[1][x] += sqz[x + 1];
            si[2][x] += sqp[x + 1];
        }
        se[0] = fmaf(ee.x, ee.x, se[0]);
        se[1] = fmaf(ee.y, ee.y, se[1]);
        // halo norm sums (idx 0 / idx 3); only lanes 0/63's values get used
        shl[0] += sqm[0]; shl[1] += sqz[0]; shl[2] += sqp[0];
        shr[0] += sqm[3]; shr[1] += sqz[3]; shr[2] += sqp[3];

        float pe[2] = { z4[1] * ee.x, z4[2] * ee.y };
#pragma unroll
        for (int x = 0; x < 2; ++x) {
            acc[0][x] = fmaf(sqm[x],     pe[x], acc[0][x]);  // (-1,-1)
            acc[1][x] = fmaf(sqm[x + 1], pe[x], acc[1][x]);  // (-1, 0)
            acc[2][x] = fmaf(sqm[x + 2], pe[x], acc[2][x]);  // (-1,+1)
            acc[3][x] = fmaf(sqz[x],     pe[x], acc[3][x]);  // ( 0,-1)
            acc[4][x] = fmaf(sqz[x + 2], pe[x], acc[4][x]);  // ( 0,+1)
            acc[5][x] = fmaf(sqp[x],     pe[x], acc[5][x]);  // (+1,-1)
            acc[6][x] = fmaf(sqp[x + 1], pe[x], acc[6][x]);  // (+1, 0)
            acc[7][x] = fmaf(sqp[x + 2], pe[x], acc[7][x]);  // (+1,+1)
        }
    }

    // ---- cross-wave tree reduction through LDS (NV floats per lane) ----
    // v: 0..15 acc[v>>1][v&1], 16..21 si[(v-16)>>1][(v-16)&1], 22..23 se,
    //    24..26 shl, 27..29 shr
#define STORE_VALS(slot)                                                     \
    {                                                                        \
        for (int k = 0; k < 8; ++k) {                                        \
            red[slot][k * 2 + 0][lane] = acc[k][0];                          \
            red[slot][k * 2 + 1][lane] = acc[k][1];                          \
        }                                                                    \
        for (int r = 0; r < 3; ++r) {                                        \
            red[slot][16 + r * 2 + 0][lane] = si[r][0];                      \
            red[slot][16 + r * 2 + 1][lane] = si[r][1];                      \
            red[slot][24 + r][lane] = shl[r];                                \
            red[slot][27 + r][lane] = shr[r];                                \
        }                                                                    \
        red[slot][22][lane] = se[0];                                         \
        red[slot][23][lane] = se[1];                                         \
    }
#define ADD_VALS(slot)                                                       \
    {                                                                        \
        for (int k = 0; k < 8; ++k) {                                        \
            acc[k][0] += red[slot][k * 2 + 0][lane];                         \
            acc[k][1] += red[slot][k * 2 + 1][lane];                         \
        }                                                                    \
        for (int r = 0; r < 3; ++r) {                                        \
            si[r][0] += red[slot][16 + r * 2 + 0][lane];                     \
            si[r][1] += red[slot][16 + r * 2 + 1][lane];                     \
            shl[r] += red[slot][24 + r][lane];                               \
            shr[r] += red[slot][27 + r][lane];                               \
        }                                                                    \
        se[0] += red[slot][22][lane];                                        \
        se[1] += red[slot][23][lane];                                        \
    }

    if (wv >= 2) STORE_VALS(wv - 2);
    __syncthreads();
    if (wv < 2) ADD_VALS(wv);
    __syncthreads();
    if (wv == 1) STORE_VALS(0);
    __syncthreads();
    if (wv != 0) return;
    ADD_VALS(0);
#undef STORE_VALS
#undef ADD_VALS

    // ---- epilogue (wave 0): reciprocal norms, windows, scale, relu ----
    float rnm[2], rnz[2], rnp[2], rnev[2];
#pragma unroll
    for (int x = 0; x < 2; ++x) {
        rnm[x] = 1.f / fmaxf(sqrtf(si[0][x]), 1e-12f);
        rnz[x] = 1.f / fmaxf(sqrtf(si[1][x]), 1e-12f);
        rnp[x] = 1.f / fmaxf(sqrtf(si[2][x]), 1e-12f);
        rnev[x] = 1.f / fmaxf(sqrtf(se[x]), 1e-12f);
    }
    // halo reciprocal norms (meaningful on lanes 0 / 63 only)
    float rhl[3], rhr[3];
#pragma unroll
    for (int r = 0; r < 3; ++r) {
        rhl[r] = 1.f / fmaxf(sqrtf(shl[r]), 1e-12f);
        rhr[r] = 1.f / fmaxf(sqrtf(shr[r]), 1e-12f);
    }

    float lnm = __shfl_up(rnm[1], 1);
    float lnz = __shfl_up(rnz[1], 1);
    float lnp = __shfl_up(rnp[1], 1);
    float rnm_ = __shfl_down(rnm[0], 1);
    float rnz_ = __shfl_down(rnz[0], 1);
    float rnp_ = __shfl_down(rnp[0], 1);
    if (lane == 0)  { lnm = rhl[0]; lnz = rhl[1]; lnp = rhl[2]; }
    if (lane == 63) { rnm_ = rhr[0]; rnz_ = rhr[1]; rnp_ = rhr[2]; }

    float nm4[4] = { lnm, rnm[0], rnm[1], rnm_ };
    float nz4[4] = { lnz, rnz[0], rnz[1], rnz_ };
    float np4[4] = { lnp, rnp[0], rnp[1], rnp_ };

    float ctr[2];
#pragma unroll
    for (int x = 0; x < 2; ++x) ctr[x] = nz4[x + 1] * rnev[x];

    float* outp = out + (((size_t)b * 8) * NH + h) * NW + w0;
#pragma unroll
    for (int k = 0; k < 8; ++k) {
        float nbv[2];
#pragma unroll
        for (int x = 0; x < 2; ++x) {
            float v;
            switch (k) {
                case 0: v = nm4[x];     break;
                case 1: v = nm4[x + 1]; break;
                case 2: v = nm4[x + 2]; break;
                case 3: v = nz4[x];     break;
                case 4: v = nz4[x + 2]; break;
                case 5: v = np4[x];     break;
                case 6: v = np4[x + 1]; break;
                default: v = np4[x + 2]; break;
            }
            nbv[x] = v;
        }
        float2 o;
        o.x = fmaxf(acc[k][0] * (nbv[0] * nbv[0]) * ctr[0], 0.f);
        o.y = fmaxf(acc[k][1] * (nbv[1] * nbv[1]) * ctr[1], 0.f);
        *(float2*)(outp + (size_t)k * NH * NW) = o;
    }
}

extern "C" void kernel_launch(void* const* d_in, const int* in_sizes, int n_in,
                              void* d_out, int out_size, void* d_ws, size_t ws_size,
                              hipStream_t stream) {
    (void)in_sizes; (void)n_in; (void)out_size; (void)d_ws; (void)ws_size;
    const float* img = (const float*)d_in[0];
    const float* ev  = (const float*)d_in[1];
    float* out = (float*)d_out;

    // 2048 blocks (b x h x 2 w-tiles), 256 threads (4 waves x 16 channels)
    k_fused<<<NB * NH * 2, 256, 0, stream>>>(img, ev, out);
}

// Round 9
// 41.385 us; speedup vs baseline: 4.1500x; 1.0970x over previous
//
#include <hip/hip_runtime.h>

// Problem constants (fixed by reference setup_inputs)
#define NB 4
#define NC 64
#define NH 256
#define NW 256
#define HW (NH * NW)            // 65536 floats per (b,c) plane
#define CPW 16                  // channels per wave (NC / 4 waves)

// R4 structure (wave-per-row, float4, 1024 blocks) + 3-buffer register
// pipeline. Grid caps occupancy at 16 waves/CU regardless of VGPR<=128, so
// spending registers on in-flight loads is free (R6 lesson: do NOT add a
// min-waves launch_bounds hint -- it clamped VGPR to 64 and spilled).
// h-edges handled branchlessly: clamped row offset + 0/1 mask multiply.
__global__ __launch_bounds__(256) void k_fused(
    const float* __restrict__ img, const float* __restrict__ ev,
    float* __restrict__ out)
{
    __shared__ float red[2][48][64];   // two reduction slots, [value][lane]

    const int lane = threadIdx.x & 63;
    const int wv   = threadIdx.x >> 6;           // 0..3 = channel chunk

    // XCD-aware swizzle: 1024 blocks, 8 XCDs -> contiguous 128-row chunks per
    // XCD so h-adjacent rows (which share img rows) live on the same L2.
    const int bid = blockIdx.x;
    const int swz = (bid & 7) * 128 + (bid >> 3);   // bijective, 1024 % 8 == 0
    const int b = swz >> 8;
    const int h = swz & 255;
    const int w = lane << 2;

    const float hmf = (h > 0) ? 1.f : 0.f;       // zero-mask for row h-1
    const float hpf = (h < NH - 1) ? 1.f : 0.f;  // zero-mask for row h+1
    const int offm = (h > 0) ? -NW : 0;          // clamped: h=0 re-reads row 0
    const int offp = (h < NH - 1) ? NW : 0;

    const size_t base = (size_t)b * NC * HW + (size_t)(wv * CPW) * HW
                      + (size_t)h * NW + w;
    const float* ibase = img + base;
    const float* ebase = ev + base;

    float acc[8][4];
    float si[3][4];
    float se[4];
#pragma unroll
    for (int k = 0; k < 8; ++k)
#pragma unroll
        for (int x = 0; x < 4; ++x) acc[k][x] = 0.f;
#pragma unroll
    for (int r = 0; r < 3; ++r)
#pragma unroll
        for (int x = 0; x < 4; ++x) si[r][x] = 0.f;
#pragma unroll
    for (int x = 0; x < 4; ++x) se[x] = 0.f;

    // ---- 3-buffer rotating pipeline: ~8 loads in flight per wave ----
    float4 Am, Az, Ap, Ae, Bm, Bz, Bp, Be, Cm, Cz, Cp, Ce;

#define LOADSET(S, c)                                                       \
    {                                                                       \
        const float* p_ = ibase + (size_t)(c) * HW;                         \
        S##m = *(const float4*)(p_ + offm);                                 \
        S##z = *(const float4*)(p_);                                        \
        S##p = *(const float4*)(p_ + offp);                                 \
        S##e = *(const float4*)(ebase + (size_t)(c) * HW);                  \
    }

#define COMPUTESET(S)                                                       \
    {                                                                       \
        float4 M = S##m, Z = S##z, P = S##p, E = S##e;                      \
        M.x *= hmf; M.y *= hmf; M.z *= hmf; M.w *= hmf;                     \
        P.x *= hpf; P.y *= hpf; P.z *= hpf; P.w *= hpf;                     \
        float lm = __shfl_up(M.w, 1);                                       \
        float lz = __shfl_up(Z.w, 1);                                       \
        float lp = __shfl_up(P.w, 1);                                       \
        float rm = __shfl_down(M.x, 1);                                     \
        float rz = __shfl_down(Z.x, 1);                                     \
        float rp = __shfl_down(P.x, 1);                                     \
        if (lane == 0)  { lm = 0.f; lz = 0.f; lp = 0.f; }                   \
        if (lane == 63) { rm = 0.f; rz = 0.f; rp = 0.f; }                   \
        float m6[6] = { lm, M.x, M.y, M.z, M.w, rm };                       \
        float z6[6] = { lz, Z.x, Z.y, Z.z, Z.w, rz };                       \
        float p6[6] = { lp, P.x, P.y, P.z, P.w, rp };                       \
        float sqm[6], sqz[6], sqp[6];                                       \
        for (int i = 0; i < 6; ++i) {                                       \
            sqm[i] = m6[i] * m6[i];                                         \
            sqz[i] = z6[i] * z6[i];                                         \
            sqp[i] = p6[i] * p6[i];                                         \
        }                                                                   \
        for (int x = 0; x < 4; ++x) {                                       \
            si[0][x] += sqm[x + 1];                                         \
            si[1][x] += sqz[x + 1];                                         \
            si[2][x] += sqp[x + 1];                                         \
        }                                                                   \
        se[0] = fmaf(E.x, E.x, se[0]);                                      \
        se[1] = fmaf(E.y, E.y, se[1]);                                      \
        se[2] = fmaf(E.z, E.z, se[2]);                                      \
        se[3] = fmaf(E.w, E.w, se[3]);                                      \
        float pe[4] = { z6[1] * E.x, z6[2] * E.y, z6[3] * E.z, z6[4] * E.w };\
        for (int x = 0; x < 4; ++x) {                                       \
            acc[0][x] = fmaf(sqm[x],     pe[x], acc[0][x]);                 \
            acc[1][x] = fmaf(sqm[x + 1], pe[x], acc[1][x]);                 \
            acc[2][x] = fmaf(sqm[x + 2], pe[x], acc[2][x]);                 \
            acc[3][x] = fmaf(sqz[x],     pe[x], acc[3][x]);                 \
            acc[4][x] = fmaf(sqz[x + 2], pe[x], acc[4][x]);                 \
            acc[5][x] = fmaf(sqp[x],     pe[x], acc[5][x]);                 \
            acc[6][x] = fmaf(sqp[x + 1], pe[x], acc[6][x]);                 \
            acc[7][x] = fmaf(sqp[x + 2], pe[x], acc[7][x]);                 \
        }                                                                   \
    }

#define STEP(S, c) { COMPUTESET(S); LOADSET(S, c); }

    LOADSET(A, 0); LOADSET(B, 1); LOADSET(C, 2);
    STEP(A, 3);  STEP(B, 4);  STEP(C, 5);
    STEP(A, 6);  STEP(B, 7);  STEP(C, 8);
    STEP(A, 9);  STEP(B, 10); STEP(C, 11);
    STEP(A, 12); STEP(B, 13); STEP(C, 14);
    STEP(A, 15);
    COMPUTESET(B); COMPUTESET(C); COMPUTESET(A);

#undef STEP
#undef LOADSET
#undef COMPUTESET

    // ---- cross-wave tree reduction through LDS (48 floats per lane) ----
    if (wv >= 2) {
        const int s = wv - 2;
#pragma unroll
        for (int k = 0; k < 8; ++k)
#pragma unroll
            for (int x = 0; x < 4; ++x) red[s][k * 4 + x][lane] = acc[k][x];
#pragma unroll
        for (int r = 0; r < 3; ++r)
#pragma unroll
            for (int x = 0; x < 4; ++x) red[s][32 + r * 4 + x][lane] = si[r][x];
#pragma unroll
        for (int x = 0; x < 4; ++x) red[s][44 + x][lane] = se[x];
    }
    __syncthreads();
    if (wv < 2) {
        const int s = wv;
#pragma unroll
        for (int k = 0; k < 8; ++k)
#pragma unroll
            for (int x = 0; x < 4; ++x) acc[k][x] += red[s][k * 4 + x][lane];
#pragma unroll
        for (int r = 0; r < 3; ++r)
#pragma unroll
            for (int x = 0; x < 4; ++x) si[r][x] += red[s][32 + r * 4 + x][lane];
#pragma unroll
        for (int x = 0; x < 4; ++x) se[x] += red[s][44 + x][lane];
    }
    __syncthreads();
    if (wv == 1) {
#pragma unroll
        for (int k = 0; k < 8; ++k)
#pragma unroll
            for (int x = 0; x < 4; ++x) red[0][k * 4 + x][lane] = acc[k][x];
#pragma unroll
        for (int r = 0; r < 3; ++r)
#pragma unroll
            for (int x = 0; x < 4; ++x) red[0][32 + r * 4 + x][lane] = si[r][x];
#pragma unroll
        for (int x = 0; x < 4; ++x) red[0][44 + x][lane] = se[x];
    }
    __syncthreads();
    if (wv != 0) return;

#pragma unroll
    for (int k = 0; k < 8; ++k)
#pragma unroll
        for (int x = 0; x < 4; ++x) acc[k][x] += red[0][k * 4 + x][lane];
#pragma unroll
    for (int r = 0; r < 3; ++r)
#pragma unroll
        for (int x = 0; x < 4; ++x) si[r][x] += red[0][32 + r * 4 + x][lane];
#pragma unroll
    for (int x = 0; x < 4; ++x) se[x] += red[0][44 + x][lane];

    // ---- epilogue (wave 0 only): reciprocal norms, windows, scale, relu ----
    float rnm[4], rnz[4], rnp[4], rne[4];
#pragma unroll
    for (int x = 0; x < 4; ++x) {
        rnm[x] = 1.f / fmaxf(sqrtf(si[0][x]), 1e-12f);
        rnz[x] = 1.f / fmaxf(sqrtf(si[1][x]), 1e-12f);
        rnp[x] = 1.f / fmaxf(sqrtf(si[2][x]), 1e-12f);
        rne[x] = 1.f / fmaxf(sqrtf(se[x]), 1e-12f);
    }

    float lnm = __shfl_up(rnm[3], 1);
    float lnz = __shfl_up(rnz[3], 1);
    float lnp = __shfl_up(rnp[3], 1);
    float rnm_ = __shfl_down(rnm[0], 1);
    float rnz_ = __shfl_down(rnz[0], 1);
    float rnp_ = __shfl_down(rnp[0], 1);
    if (lane == 0)  { lnm = 0.f; lnz = 0.f; lnp = 0.f; }
    if (lane == 63) { rnm_ = 0.f; rnz_ = 0.f; rnp_ = 0.f; }

    float nm6[6] = { lnm, rnm[0], rnm[1], rnm[2], rnm[3], rnm_ };
    float nz6[6] = { lnz, rnz[0], rnz[1], rnz[2], rnz[3], rnz_ };
    float np6[6] = { lnp, rnp[0], rnp[1], rnp[2], rnp[3], rnp_ };

    float ctr[4];
#pragma unroll
    for (int x = 0; x < 4; ++x) ctr[x] = nz6[x + 1] * rne[x];

    float* outp = out + (((size_t)b * 8) * NH + h) * NW + w;
#pragma unroll
    for (int k = 0; k < 8; ++k) {
        float nbv[4];
#pragma unroll
        for (int x = 0; x < 4; ++x) {
            float v;
            switch (k) {
                case 0: v = nm6[x];     break;
                case 1: v = nm6[x + 1]; break;
                case 2: v = nm6[x + 2]; break;
                case 3: v = nz6[x];     break;
                case 4: v = nz6[x + 2]; break;
                case 5: v = np6[x];     break;
                case 6: v = np6[x + 1]; break;
                default: v = np6[x + 2]; break;
            }
            nbv[x] = v;
        }
        float4 o;
        o.x = fmaxf(acc[k][0] * (nbv[0] * nbv[0]) * ctr[0], 0.f);
        o.y = fmaxf(acc[k][1] * (nbv[1] * nbv[1]) * ctr[1], 0.f);
        o.z = fmaxf(acc[k][2] * (nbv[2] * nbv[2]) * ctr[2], 0.f);
        o.w = fmaxf(acc[k][3] * (nbv[3] * nbv[3]) * ctr[3], 0.f);
        *(float4*)(outp + (size_t)k * NH * NW) = o;
    }
}

extern "C" void kernel_launch(void* const* d_in, const int* in_sizes, int n_in,
                              void* d_out, int out_size, void* d_ws, size_t ws_size,
                              hipStream_t stream) {
    (void)in_sizes; (void)n_in; (void)out_size; (void)d_ws; (void)ws_size;
    const float* img = (const float*)d_in[0];
    const float* ev  = (const float*)d_in[1];
    float* out = (float*)d_out;

    // 1024 blocks (one per row), 256 threads (4 waves x 16 channels)
    k_fused<<<NB * NH, 256, 0, stream>>>(img, ev, out);
}

// Round 10
// 34.144 us; speedup vs baseline: 5.0300x; 1.2121x over previous
//
#include <hip/hip_runtime.h>

// Problem constants (fixed by reference setup_inputs)
#define NB 4
#define NC 64
#define NH 256
#define NW 256
#define HW (NH * NW)            // 65536 floats per (b,c) plane
#define WAVES 8
#define CPW 8                   // channels per wave (NC / WAVES)

__device__ __forceinline__ float4 f4zero() { return make_float4(0.f, 0.f, 0.f, 0.f); }

// One block = one image row (b,h). 8 waves x 8 channels (512 threads).
// Lane owns 4 consecutive w (float4); horizontal neighbors via shuffles.
// Rationale (R4/R6/R7/R9 evidence): kernel is latency-bound; VGPR-funded MLP
// loses (R6 spills, R9 occupancy), narrower lanes lose (R7 2x instructions).
// TLP at constant VGPR: 8 waves/block -> 32 waves/CU (8/SIMD) with the VGPR-52
// R4 body unchanged. Cross-wave reduce 8->4->2->1 via two 12KB LDS slots.
__global__ __launch_bounds__(512) void k_fused(
    const float* __restrict__ img, const float* __restrict__ ev,
    float* __restrict__ out)
{
    __shared__ float red[2][48][64];   // two reduction slots, [value][lane]

    const int lane = threadIdx.x & 63;
    const int wv   = threadIdx.x >> 6;           // 0..7 = channel chunk

    // XCD-aware swizzle: 1024 blocks, 8 XCDs -> contiguous 128-row chunks per
    // XCD so h-adjacent rows (which share img rows) live on the same L2.
    const int bid = blockIdx.x;
    const int swz = (bid & 7) * 128 + (bid >> 3);   // bijective, 1024 % 8 == 0
    const int b = swz >> 8;
    const int h = swz & 255;
    const int w = lane << 2;

    const bool hm = (h > 0);
    const bool hp = (h < NH - 1);

    const size_t base = (size_t)b * NC * HW + (size_t)(wv * CPW) * HW
                      + (size_t)h * NW + w;
    const float* ibase = img + base;
    const float* ebase = ev + base;

    float acc[8][4];
    float si[3][4];
    float se[4];
#pragma unroll
    for (int k = 0; k < 8; ++k)
#pragma unroll
        for (int x = 0; x < 4; ++x) acc[k][x] = 0.f;
#pragma unroll
    for (int r = 0; r < 3; ++r)
#pragma unroll
        for (int x = 0; x < 4; ++x) si[r][x] = 0.f;
#pragma unroll
    for (int x = 0; x < 4; ++x) se[x] = 0.f;

#pragma unroll 2
    for (int c = 0; c < CPW; ++c) {
        const float* p = ibase + (size_t)c * HW;
        float4 zm = hm ? *(const float4*)(p - NW) : f4zero();
        float4 zz = *(const float4*)(p);
        float4 zp = hp ? *(const float4*)(p + NW) : f4zero();
        float4 ee = *(const float4*)(ebase + (size_t)c * HW);

        float lm = __shfl_up(zm.w, 1);
        float lz = __shfl_up(zz.w, 1);
        float lp = __shfl_up(zp.w, 1);
        float rm = __shfl_down(zm.x, 1);
        float rz = __shfl_down(zz.x, 1);
        float rp = __shfl_down(zp.x, 1);
        if (lane == 0)  { lm = 0.f; lz = 0.f; lp = 0.f; }
        if (lane == 63) { rm = 0.f; rz = 0.f; rp = 0.f; }

        // 6-wide windows: indices 0..5 cover w-1 .. w+4
        float m6[6] = { lm, zm.x, zm.y, zm.z, zm.w, rm };
        float z6[6] = { lz, zz.x, zz.y, zz.z, zz.w, rz };
        float p6[6] = { lp, zp.x, zp.y, zp.z, zp.w, rp };
        float sqm[6], sqz[6], sqp[6];
#pragma unroll
        for (int i = 0; i < 6; ++i) {
            sqm[i] = m6[i] * m6[i];
            sqz[i] = z6[i] * z6[i];
            sqp[i] = p6[i] * p6[i];
        }
#pragma unroll
        for (int x = 0; x < 4; ++x) {
            si[0][x] += sqm[x + 1];
            si[1][x] += sqz[x + 1];
            si[2][x] += sqp[x + 1];
        }
        se[0] = fmaf(ee.x, ee.x, se[0]);
        se[1] = fmaf(ee.y, ee.y, se[1]);
        se[2] = fmaf(ee.z, ee.z, se[2]);
        se[3] = fmaf(ee.w, ee.w, se[3]);

        float pe[4] = { z6[1] * ee.x, z6[2] * ee.y, z6[3] * ee.z, z6[4] * ee.w };
#pragma unroll
        for (int x = 0; x < 4; ++x) {
            acc[0][x] = fmaf(sqm[x],     pe[x], acc[0][x]);  // (-1,-1)
            acc[1][x] = fmaf(sqm[x + 1], pe[x], acc[1][x]);  // (-1, 0)
            acc[2][x] = fmaf(sqm[x + 2], pe[x], acc[2][x]);  // (-1,+1)
            acc[3][x] = fmaf(sqz[x],     pe[x], acc[3][x]);  // ( 0,-1)
            acc[4][x] = fmaf(sqz[x + 2], pe[x], acc[4][x]);  // ( 0,+1)
            acc[5][x] = fmaf(sqp[x],     pe[x], acc[5][x]);  // (+1,-1)
            acc[6][x] = fmaf(sqp[x + 1], pe[x], acc[6][x]);  // (+1, 0)
            acc[7][x] = fmaf(sqp[x + 2], pe[x], acc[7][x]);  // (+1,+1)
        }
    }

    // ---- cross-wave reduction 8->4->2->1 through two LDS slots ----
#define STORE_VALS(slot)                                                     \
    {                                                                        \
        for (int k = 0; k < 8; ++k)                                          \
            for (int x = 0; x < 4; ++x) red[slot][k * 4 + x][lane] = acc[k][x]; \
        for (int r = 0; r < 3; ++r)                                          \
            for (int x = 0; x < 4; ++x) red[slot][32 + r * 4 + x][lane] = si[r][x]; \
        for (int x = 0; x < 4; ++x) red[slot][44 + x][lane] = se[x];         \
    }
#define ADD_VALS(slot)                                                       \
    {                                                                        \
        for (int k = 0; k < 8; ++k)                                          \
            for (int x = 0; x < 4; ++x) acc[k][x] += red[slot][k * 4 + x][lane]; \
        for (int r = 0; r < 3; ++r)                                          \
            for (int x = 0; x < 4; ++x) si[r][x] += red[slot][32 + r * 4 + x][lane]; \
        for (int x = 0; x < 4; ++x) se[x] += red[slot][44 + x][lane];        \
    }

    // 8 -> 6 (waves 4,5 fold into 0,1)
    if (wv == 4) STORE_VALS(0);
    if (wv == 5) STORE_VALS(1);
    __syncthreads();
    if (wv == 0) ADD_VALS(0);
    if (wv == 1) ADD_VALS(1);
    __syncthreads();
    // waves 6,7 fold into 2,3
    if (wv == 6) STORE_VALS(0);
    if (wv == 7) STORE_VALS(1);
    __syncthreads();
    if (wv == 2) ADD_VALS(0);
    if (wv == 3) ADD_VALS(1);
    __syncthreads();
    // 4 -> 2
    if (wv == 2) STORE_VALS(0);
    if (wv == 3) STORE_VALS(1);
    __syncthreads();
    if (wv == 0) ADD_VALS(0);
    if (wv == 1) ADD_VALS(1);
    __syncthreads();
    // 2 -> 1
    if (wv == 1) STORE_VALS(0);
    __syncthreads();
    if (wv != 0) return;
    ADD_VALS(0);
#undef STORE_VALS
#undef ADD_VALS

    // ---- epilogue (wave 0 only): reciprocal norms, windows, scale, relu ----
    float rnm[4], rnz[4], rnp[4], rne[4];
#pragma unroll
    for (int x = 0; x < 4; ++x) {
        rnm[x] = 1.f / fmaxf(sqrtf(si[0][x]), 1e-12f);
        rnz[x] = 1.f / fmaxf(sqrtf(si[1][x]), 1e-12f);
        rnp[x] = 1.f / fmaxf(sqrtf(si[2][x]), 1e-12f);
        rne[x] = 1.f / fmaxf(sqrtf(se[x]), 1e-12f);
    }

    float lnm = __shfl_up(rnm[3], 1);
    float lnz = __shfl_up(rnz[3], 1);
    float lnp = __shfl_up(rnp[3], 1);
    float rnm_ = __shfl_down(rnm[0], 1);
    float rnz_ = __shfl_down(rnz[0], 1);
    float rnp_ = __shfl_down(rnp[0], 1);
    if (lane == 0)  { lnm = 0.f; lnz = 0.f; lnp = 0.f; }
    if (lane == 63) { rnm_ = 0.f; rnz_ = 0.f; rnp_ = 0.f; }

    float nm6[6] = { lnm, rnm[0], rnm[1], rnm[2], rnm[3], rnm_ };
    float nz6[6] = { lnz, rnz[0], rnz[1], rnz[2], rnz[3], rnz_ };
    float np6[6] = { lnp, rnp[0], rnp[1], rnp[2], rnp[3], rnp_ };

    float ctr[4];
#pragma unroll
    for (int x = 0; x < 4; ++x) ctr[x] = nz6[x + 1] * rne[x];

    float* outp = out + (((size_t)b * 8) * NH + h) * NW + w;
#pragma unroll
    for (int k = 0; k < 8; ++k) {
        float nbv[4];
#pragma unroll
        for (int x = 0; x < 4; ++x) {
            float v;
            switch (k) {
                case 0: v = nm6[x];     break;
                case 1: v = nm6[x + 1]; break;
                case 2: v = nm6[x + 2]; break;
                case 3: v = nz6[x];     break;
                case 4: v = nz6[x + 2]; break;
                case 5: v = np6[x];     break;
                case 6: v = np6[x + 1]; break;
                default: v = np6[x + 2]; break;
            }
            nbv[x] = v;
        }
        float4 o;
        o.x = fmaxf(acc[k][0] * (nbv[0] * nbv[0]) * ctr[0], 0.f);
        o.y = fmaxf(acc[k][1] * (nbv[1] * nbv[1]) * ctr[1], 0.f);
        o.z = fmaxf(acc[k][2] * (nbv[2] * nbv[2]) * ctr[2], 0.f);
        o.w = fmaxf(acc[k][3] * (nbv[3] * nbv[3]) * ctr[3], 0.f);
        *(float4*)(outp + (size_t)k * NH * NW) = o;
    }
}

extern "C" void kernel_launch(void* const* d_in, const int* in_sizes, int n_in,
                              void* d_out, int out_size, void* d_ws, size_t ws_size,
                              hipStream_t stream) {
    (void)in_sizes; (void)n_in; (void)out_size; (void)d_ws; (void)ws_size;
    const float* img = (const float*)d_in[0];
    const float* ev  = (const float*)d_in[1];
    float* out = (float*)d_out;

    // 1024 blocks (one per row), 512 threads (8 waves x 8 channels)
    k_fused<<<NB * NH, 512, 0, stream>>>(img, ev, out);
}

// Round 11
// 32.378 us; speedup vs baseline: 5.3043x; 1.0545x over previous
//
#include <hip/hip_runtime.h>

// Problem constants (fixed by reference setup_inputs)
#define NB 4
#define NC 64
#define NH 256
#define NW 256
#define HW (NH * NW)          // 65536 floats per (b,c) plane
#define RPB 4                 // output rows per block
#define CSTEP 4               // channels staged per step
#define NSTEP (NC / CSTEP)    // 16 steps

// Evidence trail: R4/R10 showed per-CU outstanding-miss saturation (2x waves
// -> +3% VALUBusy); R9 showed VGPR-funded MLP loses occupancy. Fix: reduce
// logical bytes. Each img row was read 3x (by blocks h-1,h,h+1); this block
// covers 4 rows and stages each needed row ONCE into LDS (6 img + 4 ev rows
// per channel), so logical traffic drops 256MB -> 160MB. 128KB LDS forces
// exactly 1 block/CU on a 256-block grid.
__device__ __forceinline__ void gload_lds16(const float* g, float* l) {
    __builtin_amdgcn_global_load_lds(
        (const __attribute__((address_space(1))) void*)g,
        (__attribute__((address_space(3))) void*)l, 16, 0, 0);
}

__global__ __launch_bounds__(512) void k_fused(
    const float* __restrict__ img, const float* __restrict__ ev,
    float* __restrict__ out)
{
    __shared__ float lds[2][CSTEP][10][NW];   // 80 KB: rows 0..5 img (h0-1..h0+4), 6..9 ev (h0..h0+3)
    __shared__ float redbuf[RPB][48][64];     // 48 KB: 2-way channel reduction; total 128 KB

    const int lane = threadIdx.x & 63;
    const int wv   = threadIdx.x >> 6;        // 0..7
    const int row  = wv >> 1;                 // 0..3: output row within tile
    const int g    = wv & 1;                  // channel half within a step

    // XCD swizzle: 256 blocks, 8 XCDs; consecutive h-tiles share halo rows in L2.
    const int bid = blockIdx.x;
    const int swz = (bid & 7) * 32 + (bid >> 3);   // bijective, 256 % 8 == 0
    const int b   = swz >> 6;
    const int h0  = (swz & 63) << 2;
    const int h   = h0 + row;
    const int w   = lane << 2;

    const float hmf = (h > 0) ? 1.f : 0.f;         // zero-mask row h-1
    const float hpf = (h < NH - 1) ? 1.f : 0.f;    // zero-mask row h+1

    const size_t ibb = (size_t)b * NC * HW;
    const float* gimg = img + ibb;
    const float* gev  = ev + ibb;

    float acc[8][4], si[3][4], se[4];
#pragma unroll
    for (int k = 0; k < 8; ++k)
#pragma unroll
        for (int x = 0; x < 4; ++x) acc[k][x] = 0.f;
#pragma unroll
    for (int r = 0; r < 3; ++r)
#pragma unroll
        for (int x = 0; x < 4; ++x) si[r][x] = 0.f;
#pragma unroll
    for (int x = 0; x < 4; ++x) se[x] = 0.f;

    // Stage step snext into buffer snext&1: 40 row-loads (4ch x 10 rows),
    // 5 per wave, each 1 KB via global_load_lds width-16 (lane*16B, linear).
#define STAGE(snext)                                                         \
    {                                                                        \
        const int bufi_ = (snext) & 1;                                       \
        _Pragma("unroll")                                                    \
        for (int j = 0; j < 5; ++j) {                                        \
            const int t  = wv * 5 + j;                                       \
            const int cc = t / 10;                                           \
            const int r  = t - cc * 10;                                      \
            const int c  = (snext) * CSTEP + cc;                             \
            const float* src;                                                \
            if (r < 6) {                                                     \
                int sr = h0 - 1 + r;                                         \
                sr = sr < 0 ? 0 : (sr > NH - 1 ? NH - 1 : sr);               \
                src = gimg + (size_t)c * HW + (size_t)sr * NW;               \
            } else {                                                         \
                src = gev + (size_t)c * HW + (size_t)(h0 + r - 6) * NW;      \
            }                                                                \
            gload_lds16(src + lane * 4, &lds[bufi_][cc][r][0]);              \
        }                                                                    \
    }

    // Compute one channel from LDS (verified R4 math; masks like passing R9).
#define COMPUTECH(bufi, cc)                                                  \
    {                                                                        \
        const float4* Mp = (const float4*)&lds[bufi][cc][row + 0][0];        \
        const float4* Zp = (const float4*)&lds[bufi][cc][row + 1][0];        \
        const float4* Pp = (const float4*)&lds[bufi][cc][row + 2][0];        \
        const float4* Ep = (const float4*)&lds[bufi][cc][6 + row][0];        \
        float4 M = Mp[lane], Z = Zp[lane], P = Pp[lane], E = Ep[lane];       \
        M.x *= hmf; M.y *= hmf; M.z *= hmf; M.w *= hmf;                      \
        P.x *= hpf; P.y *= hpf; P.z *= hpf; P.w *= hpf;                      \
        float lm = __shfl_up(M.w, 1);                                        \
        float lz = __shfl_up(Z.w, 1);                                        \
        float lp = __shfl_up(P.w, 1);                                        \
        float rm = __shfl_down(M.x, 1);                                      \
        float rz = __shfl_down(Z.x, 1);                                      \
        float rp = __shfl_down(P.x, 1);                                      \
        if (lane == 0)  { lm = 0.f; lz = 0.f; lp = 0.f; }                    \
        if (lane == 63) { rm = 0.f; rz = 0.f; rp = 0.f; }                    \
        float m6[6] = { lm, M.x, M.y, M.z, M.w, rm };                        \
        float z6[6] = { lz, Z.x, Z.y, Z.z, Z.w, rz };                        \
        float p6[6] = { lp, P.x, P.y, P.z, P.w, rp };                        \
        float sqm[6], sqz[6], sqp[6];                                        \
        for (int i = 0; i < 6; ++i) {                                        \
            sqm[i] = m6[i] * m6[i];                                          \
            sqz[i] = z6[i] * z6[i];                                          \
            sqp[i] = p6[i] * p6[i];                                          \
        }                                                                    \
        for (int x = 0; x < 4; ++x) {                                        \
            si[0][x] += sqm[x + 1];                                          \
            si[1][x] += sqz[x + 1];                                          \
            si[2][x] += sqp[x + 1];                                          \
        }                                                                    \
        se[0] = fmaf(E.x, E.x, se[0]);                                       \
        se[1] = fmaf(E.y, E.y, se[1]);                                       \
        se[2] = fmaf(E.z, E.z, se[2]);                                       \
        se[3] = fmaf(E.w, E.w, se[3]);                                       \
        float pe[4] = { z6[1] * E.x, z6[2] * E.y, z6[3] * E.z, z6[4] * E.w };\
        for (int x = 0; x < 4; ++x) {                                        \
            acc[0][x] = fmaf(sqm[x],     pe[x], acc[0][x]);                  \
            acc[1][x] = fmaf(sqm[x + 1], pe[x], acc[1][x]);                  \
            acc[2][x] = fmaf(sqm[x + 2], pe[x], acc[2][x]);                  \
            acc[3][x] = fmaf(sqz[x],     pe[x], acc[3][x]);                  \
            acc[4][x] = fmaf(sqz[x + 2], pe[x], acc[4][x]);                  \
            acc[5][x] = fmaf(sqp[x],     pe[x], acc[5][x]);                  \
            acc[6][x] = fmaf(sqp[x + 1], pe[x], acc[6][x]);                  \
            acc[7][x] = fmaf(sqp[x + 2], pe[x], acc[7][x]);                  \
        }                                                                    \
    }

    STAGE(0);
    __syncthreads();                       // drain prologue stage
    for (int s = 0; s < NSTEP; ++s) {
        if (s + 1 < NSTEP) STAGE(s + 1);   // next step's loads in flight
        const int bufi = s & 1;
        const int c0 = g * 2;
        COMPUTECH(bufi, c0);
        COMPUTECH(bufi, c0 + 1);
        __syncthreads();                   // also drains stage(s+1) vmcnt
    }
#undef STAGE
#undef COMPUTECH

    // ---- 2-way channel-half reduction via redbuf ----
    if (g == 1) {
#pragma unroll
        for (int k = 0; k < 8; ++k)
#pragma unroll
            for (int x = 0; x < 4; ++x) redbuf[row][k * 4 + x][lane] = acc[k][x];
#pragma unroll
        for (int r = 0; r < 3; ++r)
#pragma unroll
            for (int x = 0; x < 4; ++x) redbuf[row][32 + r * 4 + x][lane] = si[r][x];
#pragma unroll
        for (int x = 0; x < 4; ++x) redbuf[row][44 + x][lane] = se[x];
    }
    __syncthreads();
    if (g == 1) return;
#pragma unroll
    for (int k = 0; k < 8; ++k)
#pragma unroll
        for (int x = 0; x < 4; ++x) acc[k][x] += redbuf[row][k * 4 + x][lane];
#pragma unroll
    for (int r = 0; r < 3; ++r)
#pragma unroll
        for (int x = 0; x < 4; ++x) si[r][x] += redbuf[row][32 + r * 4 + x][lane];
#pragma unroll
    for (int x = 0; x < 4; ++x) se[x] += redbuf[row][44 + x][lane];

    // ---- epilogue (one wave per row): reciprocal norms, windows, relu ----
    float rnm[4], rnz[4], rnp[4], rne[4];
#pragma unroll
    for (int x = 0; x < 4; ++x) {
        rnm[x] = 1.f / fmaxf(sqrtf(si[0][x]), 1e-12f);
        rnz[x] = 1.f / fmaxf(sqrtf(si[1][x]), 1e-12f);
        rnp[x] = 1.f / fmaxf(sqrtf(si[2][x]), 1e-12f);
        rne[x] = 1.f / fmaxf(sqrtf(se[x]), 1e-12f);
    }

    float lnm = __shfl_up(rnm[3], 1);
    float lnz = __shfl_up(rnz[3], 1);
    float lnp = __shfl_up(rnp[3], 1);
    float rnm_ = __shfl_down(rnm[0], 1);
    float rnz_ = __shfl_down(rnz[0], 1);
    float rnp_ = __shfl_down(rnp[0], 1);
    if (lane == 0)  { lnm = 0.f; lnz = 0.f; lnp = 0.f; }
    if (lane == 63) { rnm_ = 0.f; rnz_ = 0.f; rnp_ = 0.f; }

    float nm6[6] = { lnm, rnm[0], rnm[1], rnm[2], rnm[3], rnm_ };
    float nz6[6] = { lnz, rnz[0], rnz[1], rnz[2], rnz[3], rnz_ };
    float np6[6] = { lnp, rnp[0], rnp[1], rnp[2], rnp[3], rnp_ };

    float ctr[4];
#pragma unroll
    for (int x = 0; x < 4; ++x) ctr[x] = nz6[x + 1] * rne[x];

    float* outp = out + (((size_t)b * 8) * NH + h) * NW + w;
#pragma unroll
    for (int k = 0; k < 8; ++k) {
        float nbv[4];
#pragma unroll
        for (int x = 0; x < 4; ++x) {
            float v;
            switch (k) {
                case 0: v = nm6[x];     break;
                case 1: v = nm6[x + 1]; break;
                case 2: v = nm6[x + 2]; break;
                case 3: v = nz6[x];     break;
                case 4: v = nz6[x + 2]; break;
                case 5: v = np6[x];     break;
                case 6: v = np6[x + 1]; break;
                default: v = np6[x + 2]; break;
            }
            nbv[x] = v;
        }
        float4 o;
        o.x = fmaxf(acc[k][0] * (nbv[0] * nbv[0]) * ctr[0], 0.f);
        o.y = fmaxf(acc[k][1] * (nbv[1] * nbv[1]) * ctr[1], 0.f);
        o.z = fmaxf(acc[k][2] * (nbv[2] * nbv[2]) * ctr[2], 0.f);
        o.w = fmaxf(acc[k][3] * (nbv[3] * nbv[3]) * ctr[3], 0.f);
        *(float4*)(outp + (size_t)k * NH * NW) = o;
    }
}

extern "C" void kernel_launch(void* const* d_in, const int* in_sizes, int n_in,
                              void* d_out, int out_size, void* d_ws, size_t ws_size,
                              hipStream_t stream) {
    (void)in_sizes; (void)n_in; (void)out_size; (void)d_ws; (void)ws_size;
    const float* img = (const float*)d_in[0];
    const float* ev  = (const float*)d_in[1];
    float* out = (float*)d_out;

    // 256 blocks (4 batches x 64 h-tiles of 4 rows), 512 threads (8 waves)
    k_fused<<<NB * (NH / RPB), 512, 0, stream>>>(img, ev, out);
}

// Round 12
// 31.174 us; speedup vs baseline: 5.5091x; 1.0386x over previous
//
#include <hip/hip_runtime.h>

// Problem constants (fixed by reference setup_inputs)
#define NB 4
#define NC 64
#define NH 256
#define NW 256
#define HW (NH * NW)          // 65536 floats per (b,c) plane
#define RPB 4                 // rows per block
#define CPW 16                // channels per wave (NC / 4 quarters)

// Evidence: R4(16w/CU)=30.4us ~ R10(32w/CU)=34.1us, VALUBusy 17-21% both ->
// per-CU memory concurrency (MSHR) saturated; TLP/MLP dead ends (R6/R9 VGPR
// regressions). R11 LDS staging cut logical bytes but __syncthreads drained
// vmcnt every step -> un-overlapped. R12: same R4 instruction mix, but the
// 3 waves that read the same img row sit in the SAME block at the SAME loop
// position -> L1 (32KB/CU) serves the 2 reuse reads at ~30cyc instead of
// L2/L3 at ~700cyc. Block = 4 rows x 4 channel-quarters = 16 waves (1024thr),
// grid 256 = 1 block/CU. Per-row 4->2->1 reduction via LDS (R10 pattern).
__global__ __launch_bounds__(1024) void k_fused(
    const float* __restrict__ img, const float* __restrict__ ev,
    float* __restrict__ out)
{
    __shared__ float red[RPB][2][48][64];   // 98 KB: per-row two reduction slots

    const int lane = threadIdx.x & 63;
    const int wv   = threadIdx.x >> 6;       // 0..15
    const int row  = wv >> 2;                // 0..3 output row in tile
    const int q    = wv & 3;                 // channel quarter

    // XCD swizzle: 256 blocks, 8 XCDs; consecutive h-tiles share halo rows in L2.
    const int bid = blockIdx.x;
    const int swz = (bid & 7) * 32 + (bid >> 3);   // bijective, 256 % 8 == 0
    const int b   = swz >> 6;
    const int h0  = (swz & 63) << 2;
    const int h   = h0 + row;
    const int w   = lane << 2;

    const float hmf = (h > 0) ? 1.f : 0.f;        // zero-mask row h-1
    const float hpf = (h < NH - 1) ? 1.f : 0.f;   // zero-mask row h+1
    const int offm = (h > 0) ? -NW : 0;           // clamped offsets (verified R9/R11)
    const int offp = (h < NH - 1) ? NW : 0;

    const size_t base = (size_t)b * NC * HW + (size_t)(q * CPW) * HW
                      + (size_t)h * NW + w;
    const float* ibase = img + base;
    const float* ebase = ev + base;

    float acc[8][4], si[3][4], se[4];
#pragma unroll
    for (int k = 0; k < 8; ++k)
#pragma unroll
        for (int x = 0; x < 4; ++x) acc[k][x] = 0.f;
#pragma unroll
    for (int r = 0; r < 3; ++r)
#pragma unroll
        for (int x = 0; x < 4; ++x) si[r][x] = 0.f;
#pragma unroll
    for (int x = 0; x < 4; ++x) se[x] = 0.f;

#pragma unroll 2
    for (int c = 0; c < CPW; ++c) {
        const float* p = ibase + (size_t)c * HW;
        float4 M = *(const float4*)(p + offm);
        float4 Z = *(const float4*)(p);
        float4 P = *(const float4*)(p + offp);
        float4 E = *(const float4*)(ebase + (size_t)c * HW);
        M.x *= hmf; M.y *= hmf; M.z *= hmf; M.w *= hmf;
        P.x *= hpf; P.y *= hpf; P.z *= hpf; P.w *= hpf;

        float lm = __shfl_up(M.w, 1);
        float lz = __shfl_up(Z.w, 1);
        float lp = __shfl_up(P.w, 1);
        float rm = __shfl_down(M.x, 1);
        float rz = __shfl_down(Z.x, 1);
        float rp = __shfl_down(P.x, 1);
        if (lane == 0)  { lm = 0.f; lz = 0.f; lp = 0.f; }
        if (lane == 63) { rm = 0.f; rz = 0.f; rp = 0.f; }

        // 6-wide windows: indices 0..5 cover w-1 .. w+4
        float m6[6] = { lm, M.x, M.y, M.z, M.w, rm };
        float z6[6] = { lz, Z.x, Z.y, Z.z, Z.w, rz };
        float p6[6] = { lp, P.x, P.y, P.z, P.w, rp };
        float sqm[6], sqz[6], sqp[6];
#pragma unroll
        for (int i = 0; i < 6; ++i) {
            sqm[i] = m6[i] * m6[i];
            sqz[i] = z6[i] * z6[i];
            sqp[i] = p6[i] * p6[i];
        }
#pragma unroll
        for (int x = 0; x < 4; ++x) {
            si[0][x] += sqm[x + 1];
            si[1][x] += sqz[x + 1];
            si[2][x] += sqp[x + 1];
        }
        se[0] = fmaf(E.x, E.x, se[0]);
        se[1] = fmaf(E.y, E.y, se[1]);
        se[2] = fmaf(E.z, E.z, se[2]);
        se[3] = fmaf(E.w, E.w, se[3]);

        float pe[4] = { z6[1] * E.x, z6[2] * E.y, z6[3] * E.z, z6[4] * E.w };
#pragma unroll
        for (int x = 0; x < 4; ++x) {
            acc[0][x] = fmaf(sqm[x],     pe[x], acc[0][x]);  // (-1,-1)
            acc[1][x] = fmaf(sqm[x + 1], pe[x], acc[1][x]);  // (-1, 0)
            acc[2][x] = fmaf(sqm[x + 2], pe[x], acc[2][x]);  // (-1,+1)
            acc[3][x] = fmaf(sqz[x],     pe[x], acc[3][x]);  // ( 0,-1)
            acc[4][x] = fmaf(sqz[x + 2], pe[x], acc[4][x]);  // ( 0,+1)
            acc[5][x] = fmaf(sqp[x],     pe[x], acc[5][x]);  // (+1,-1)
            acc[6][x] = fmaf(sqp[x + 1], pe[x], acc[6][x]);  // (+1, 0)
            acc[7][x] = fmaf(sqp[x + 2], pe[x], acc[7][x]);  // (+1,+1)
        }
    }

    // ---- per-row 4->2->1 reduction through LDS ----
#define STORE_VALS(slot)                                                     \
    {                                                                        \
        for (int k = 0; k < 8; ++k)                                          \
            for (int x = 0; x < 4; ++x) red[row][slot][k * 4 + x][lane] = acc[k][x]; \
        for (int r = 0; r < 3; ++r)                                          \
            for (int x = 0; x < 4; ++x) red[row][slot][32 + r * 4 + x][lane] = si[r][x]; \
        for (int x = 0; x < 4; ++x) red[row][slot][44 + x][lane] = se[x];    \
    }
#define ADD_VALS(slot)                                                       \
    {                                                                        \
        for (int k = 0; k < 8; ++k)                                          \
            for (int x = 0; x < 4; ++x) acc[k][x] += red[row][slot][k * 4 + x][lane]; \
        for (int r = 0; r < 3; ++r)                                          \
            for (int x = 0; x < 4; ++x) si[r][x] += red[row][slot][32 + r * 4 + x][lane]; \
        for (int x = 0; x < 4; ++x) se[x] += red[row][slot][44 + x][lane];   \
    }

    if (q == 2) STORE_VALS(0);
    if (q == 3) STORE_VALS(1);
    __syncthreads();
    if (q == 0) ADD_VALS(0);
    if (q == 1) ADD_VALS(1);
    __syncthreads();
    if (q == 1) STORE_VALS(0);
    __syncthreads();
    if (q != 0) return;
    ADD_VALS(0);
#undef STORE_VALS
#undef ADD_VALS

    // ---- epilogue (wave q==0 of each row): norms, windows, scale, relu ----
    float rnm[4], rnz[4], rnp[4], rne[4];
#pragma unroll
    for (int x = 0; x < 4; ++x) {
        rnm[x] = 1.f / fmaxf(sqrtf(si[0][x]), 1e-12f);
        rnz[x] = 1.f / fmaxf(sqrtf(si[1][x]), 1e-12f);
        rnp[x] = 1.f / fmaxf(sqrtf(si[2][x]), 1e-12f);
        rne[x] = 1.f / fmaxf(sqrtf(se[x]), 1e-12f);
    }

    float lnm = __shfl_up(rnm[3], 1);
    float lnz = __shfl_up(rnz[3], 1);
    float lnp = __shfl_up(rnp[3], 1);
    float rnm_ = __shfl_down(rnm[0], 1);
    float rnz_ = __shfl_down(rnz[0], 1);
    float rnp_ = __shfl_down(rnp[0], 1);
    if (lane == 0)  { lnm = 0.f; lnz = 0.f; lnp = 0.f; }
    if (lane == 63) { rnm_ = 0.f; rnz_ = 0.f; rnp_ = 0.f; }

    float nm6[6] = { lnm, rnm[0], rnm[1], rnm[2], rnm[3], rnm_ };
    float nz6[6] = { lnz, rnz[0], rnz[1], rnz[2], rnz[3], rnz_ };
    float np6[6] = { lnp, rnp[0], rnp[1], rnp[2], rnp[3], rnp_ };

    float ctr[4];
#pragma unroll
    for (int x = 0; x < 4; ++x) ctr[x] = nz6[x + 1] * rne[x];

    float* outp = out + (((size_t)b * 8) * NH + h) * NW + w;
#pragma unroll
    for (int k = 0; k < 8; ++k) {
        float nbv[4];
#pragma unroll
        for (int x = 0; x < 4; ++x) {
            float v;
            switch (k) {
                case 0: v = nm6[x];     break;
                case 1: v = nm6[x + 1]; break;
                case 2: v = nm6[x + 2]; break;
                case 3: v = nz6[x];     break;
                case 4: v = nz6[x + 2]; break;
                case 5: v = np6[x];     break;
                case 6: v = np6[x + 1]; break;
                default: v = np6[x + 2]; break;
            }
            nbv[x] = v;
        }
        float4 o;
        o.x = fmaxf(acc[k][0] * (nbv[0] * nbv[0]) * ctr[0], 0.f);
        o.y = fmaxf(acc[k][1] * (nbv[1] * nbv[1]) * ctr[1], 0.f);
        o.z = fmaxf(acc[k][2] * (nbv[2] * nbv[2]) * ctr[2], 0.f);
        o.w = fmaxf(acc[k][3] * (nbv[3] * nbv[3]) * ctr[3], 0.f);
        *(float4*)(outp + (size_t)k * NH * NW) = o;
    }
}

extern "C" void kernel_launch(void* const* d_in, const int* in_sizes, int n_in,
                              void* d_out, int out_size, void* d_ws, size_t ws_size,
                              hipStream_t stream) {
    (void)in_sizes; (void)n_in; (void)out_size; (void)d_ws; (void)ws_size;
    const float* img = (const float*)d_in[0];
    const float* ev  = (const float*)d_in[1];
    float* out = (float*)d_out;

    // 256 blocks (4 batches x 64 h-tiles of 4 rows), 1024 threads (16 waves)
    k_fused<<<NB * (NH / RPB), 1024, 0, stream>>>(img, ev, out);
}